// Round 3
// baseline (437.349 us; speedup 1.0000x reference)
//
#include <hip/hip_runtime.h>
#include <math.h>

#define NTOK 512      // N
#define BATCH 2
#define HID 256
#define HEADS 4
#define HD 64
#define NEG_INF -1e9f

// Branch-free gelu via Abramowitz-Stegun 7.1.26 erf (max erf err 1.5e-7).
__device__ __forceinline__ float fast_gelu(float x) {
    const float z = fabsf(x) * 0.70710678118654752f;
    const float t = __builtin_amdgcn_rcpf(fmaf(0.3275911f, z, 1.0f));
    float p = fmaf(1.061405429f, t, -1.453152027f);
    p = fmaf(p, t, 1.421413741f);
    p = fmaf(p, t, -0.284496736f);
    p = fmaf(p, t, 0.254829592f);
    p = p * t;
    const float E = __expf(-(z * z));
    const float phin = 0.5f * p * E;                 // Phi(-|x|)
    const float phi = (x >= 0.0f) ? 1.0f - phin : phin;
    return x * phi;
}

__device__ __forceinline__ float lane_bcast(float v, int l) {
    return __int_as_float(__builtin_amdgcn_readlane(__float_as_int(v), l));
}

// ---------------------------------------------------------------------------
// Stage 0: compact valid (i,j) pairs of adj into a flat worklist.
//   grid = 512 (row i), block = 64 (one wave). Order nondeterministic
//   (atomic slab allocation) but the SET of pairs — and hence all outputs —
//   is deterministic.
// ---------------------------------------------------------------------------
__global__ void pga_compact(const int* __restrict__ adj,
                            int* __restrict__ pairs, int* __restrict__ gcount)
{
    const int i = blockIdx.x;
    const int lane = threadIdx.x;
    for (int c = 0; c < 8; ++c) {
        const int j = c * 64 + lane;
        const bool m = adj[i * NTOK + j] > 0;
        const unsigned long long bm = __ballot(m);
        const int cnt = __popcll(bm);
        int base = 0;
        if (lane == 0 && cnt) base = atomicAdd(gcount, cnt);
        base = __shfl(base, 0, 64);
        if (m) pairs[base + __popcll(bm & ((1ull << lane) - 1ull))] = (i << 10) | j;
    }
}

// ---------------------------------------------------------------------------
// Stage A: fused 5-way projection GEMM.  Y = X @ W (+bias)
//   4x4 register tile per thread: cg = cols 4cg..4cg+3, rg = rows 4rg..4rg+3
// ---------------------------------------------------------------------------
__global__ __launch_bounds__(256) void pga_proj5(
    const float* __restrict__ x,
    const float* __restrict__ Wq, const float* __restrict__ bq,
    const float* __restrict__ Wk, const float* __restrict__ bk,
    const float* __restrict__ Wv, const float* __restrict__ bv,
    const float* __restrict__ Wp1, const float* __restrict__ bp1,
    float* __restrict__ Q, float* __restrict__ K, float* __restrict__ V,
    float* __restrict__ A, float* __restrict__ BbT)
{
    __shared__ float xs[16][HID];
    const int m0 = blockIdx.x * 16;
    const int which = blockIdx.y;
    const int t = threadIdx.x;
    const int cg = t & 63;
    const int rg = t >> 6;

    {   // stage x tile: 1024 float4
        const float4* xg = (const float4*)(x + m0 * HID);
        float4* xsv = (float4*)xs;
        #pragma unroll
        for (int k = 0; k < 4; ++k) xsv[t + 256 * k] = xg[t + 256 * k];
    }
    __syncthreads();

    const float* W; const float* bvec; float* out; bool transposed = false;
    switch (which) {
        case 0: W = Wq; bvec = bq; out = Q; break;
        case 1: W = Wk; bvec = bk; out = K; break;
        case 2: W = Wv; bvec = bv; out = V; break;
        case 3: W = Wp1; bvec = bp1; out = A; break;
        default: W = Wp1 + HID * HID; bvec = nullptr; out = BbT; transposed = true; break;
    }

    float4 bias4 = make_float4(0.f, 0.f, 0.f, 0.f);
    if (bvec) bias4 = ((const float4*)bvec)[cg];
    float4 acc[4] = {bias4, bias4, bias4, bias4};

    const float4* W4 = (const float4*)W;
    for (int kq = 0; kq < 64; ++kq) {
        const float4 w0 = W4[(4 * kq + 0) * 64 + cg];
        const float4 w1 = W4[(4 * kq + 1) * 64 + cg];
        const float4 w2 = W4[(4 * kq + 2) * 64 + cg];
        const float4 w3 = W4[(4 * kq + 3) * 64 + cg];
        #pragma unroll
        for (int r = 0; r < 4; ++r) {
            const float4 xv = ((const float4*)xs[4 * rg + r])[kq];
            acc[r].x = fmaf(xv.x, w0.x, fmaf(xv.y, w1.x, fmaf(xv.z, w2.x, fmaf(xv.w, w3.x, acc[r].x))));
            acc[r].y = fmaf(xv.x, w0.y, fmaf(xv.y, w1.y, fmaf(xv.z, w2.y, fmaf(xv.w, w3.y, acc[r].y))));
            acc[r].z = fmaf(xv.x, w0.z, fmaf(xv.y, w1.z, fmaf(xv.z, w2.z, fmaf(xv.w, w3.z, acc[r].z))));
            acc[r].w = fmaf(xv.x, w0.w, fmaf(xv.y, w1.w, fmaf(xv.z, w2.w, fmaf(xv.w, w3.w, acc[r].w))));
        }
    }

    if (!transposed) {
        #pragma unroll
        for (int r = 0; r < 4; ++r)
            ((float4*)(out + (m0 + 4 * rg + r) * HID))[cg] = acc[r];
    } else {
        const int b = m0 >= NTOK;
        const int n0 = m0 - b * NTOK;
        #pragma unroll
        for (int r = 0; r < 4; ++r) {
            const int row = n0 + 4 * rg + r;
            float* ob = BbT + b * (HID * NTOK);
            ob[(4 * cg + 0) * NTOK + row] = acc[r].x;
            ob[(4 * cg + 1) * NTOK + row] = acc[r].y;
            ob[(4 * cg + 2) * NTOK + row] = acc[r].z;
            ob[(4 * cg + 3) * NTOK + row] = acc[r].w;
        }
    }
}

// ---------------------------------------------------------------------------
// Stage B: physics bias over VALID pairs only.
//   grid = 2*1024 blocks x 256 threads; thread idx -> pairs[idx] (i,j), b from blk.
// ---------------------------------------------------------------------------
__global__ __launch_bounds__(256) void pga_bias(
    const float* __restrict__ A, const float* __restrict__ BbT,
    const float* __restrict__ Wp2, const float* __restrict__ bp2,
    const int* __restrict__ pairs, const int* __restrict__ gcount,
    float* __restrict__ biasg)
{
    const int t = threadIdx.x;
    const int blk = blockIdx.x;
    const int b = blk >> 10;
    const int idx = (blk & 1023) * 256 + t;
    if (idx >= *gcount) return;
    const int pr = pairs[idx];
    const int i = pr >> 10, j = pr & 1023;

    const float4* A4 = (const float4*)(A + (b * NTOK + i) * HID);
    const float* bb = BbT + b * (HID * NTOK) + j;
    const float4* W4 = (const float4*)Wp2;   // wave-uniform index -> s_load

    float ah0 = 0.f, ah1 = 0.f, ah2 = 0.f, ah3 = 0.f;
    #pragma unroll 2
    for (int dq = 0; dq < 64; ++dq) {
        const float4 a4 = A4[dq];
        {
            const float g = fast_gelu(a4.x + bb[(4 * dq + 0) * NTOK]);
            const float4 wv = W4[4 * dq + 0];
            ah0 = fmaf(g, wv.x, ah0); ah1 = fmaf(g, wv.y, ah1);
            ah2 = fmaf(g, wv.z, ah2); ah3 = fmaf(g, wv.w, ah3);
        }
        {
            const float g = fast_gelu(a4.y + bb[(4 * dq + 1) * NTOK]);
            const float4 wv = W4[4 * dq + 1];
            ah0 = fmaf(g, wv.x, ah0); ah1 = fmaf(g, wv.y, ah1);
            ah2 = fmaf(g, wv.z, ah2); ah3 = fmaf(g, wv.w, ah3);
        }
        {
            const float g = fast_gelu(a4.z + bb[(4 * dq + 2) * NTOK]);
            const float4 wv = W4[4 * dq + 2];
            ah0 = fmaf(g, wv.x, ah0); ah1 = fmaf(g, wv.y, ah1);
            ah2 = fmaf(g, wv.z, ah2); ah3 = fmaf(g, wv.w, ah3);
        }
        {
            const float g = fast_gelu(a4.w + bb[(4 * dq + 3) * NTOK]);
            const float4 wv = W4[4 * dq + 3];
            ah0 = fmaf(g, wv.x, ah0); ah1 = fmaf(g, wv.y, ah1);
            ah2 = fmaf(g, wv.z, ah2); ah3 = fmaf(g, wv.w, ah3);
        }
    }

    const float4 bp = *(const float4*)bp2;
    float* o = biasg + (((size_t)b * HEADS) * NTOK + i) * NTOK + j;
    o[0 * NTOK * NTOK] = ah0 + bp.x;
    o[1 * NTOK * NTOK] = ah1 + bp.y;
    o[2 * NTOK * NTOK] = ah2 + bp.z;
    o[3 * NTOK * NTOK] = ah3 + bp.w;
}

// ---------------------------------------------------------------------------
// Stage C: attention.  grid = B*H*(N/8) = 512 blocks, 256 threads (4 waves)
//   wave w handles rows ia = i0+2w, ib = ia+1 — K/V LDS reads amortized 2x.
// ---------------------------------------------------------------------------
__global__ __launch_bounds__(256) void pga_attn(
    const float* __restrict__ Q, const float* __restrict__ K,
    const float* __restrict__ V, const float* __restrict__ biasg,
    const int* __restrict__ adj, float* __restrict__ O)
{
    __shared__ float Ks[128][HD + 4];
    __shared__ float qs[8][HD];

    const int blk = blockIdx.x;
    const int i0 = (blk & 63) * 8;
    const int h = (blk >> 6) & 3;
    const int b = blk >> 8;
    const int t = threadIdx.x;
    const int w = t >> 6;
    const int lane = t & 63;
    const int ia = i0 + 2 * w, ib = ia + 1;

    for (int idx = t; idx < 8 * HD; idx += 256) {
        int r = idx >> 6, d = idx & 63;
        qs[r][d] = Q[(b * NTOK + i0 + r) * HID + h * HD + d];
    }

    const float scale = 0.125f;
    float S[2][8];

    // ---- phase 1: scores for both rows, all 512 j ----
    for (int jt = 0; jt < 4; ++jt) {
        __syncthreads();
        for (int idx = t; idx < 128 * 16; idx += 256) {
            int r = idx >> 4, dq = idx & 15;
            ((float4*)Ks[r])[dq] =
                ((const float4*)(K + (b * NTOK + jt * 128 + r) * HID + h * HD))[dq];
        }
        __syncthreads();
        float a00 = 0.f, a01 = 0.f, a10 = 0.f, a11 = 0.f;
        const float4* q0v = (const float4*)qs[2 * w];
        const float4* q1v = (const float4*)qs[2 * w + 1];
        const float4* k0v = (const float4*)Ks[lane];
        const float4* k1v = (const float4*)Ks[64 + lane];
        #pragma unroll
        for (int dq = 0; dq < 16; ++dq) {
            const float4 q0 = q0v[dq], q1 = q1v[dq];
            const float4 k0 = k0v[dq], k1 = k1v[dq];
            a00 += q0.x * k0.x + q0.y * k0.y + q0.z * k0.z + q0.w * k0.w;
            a01 += q0.x * k1.x + q0.y * k1.y + q0.z * k1.z + q0.w * k1.w;
            a10 += q1.x * k0.x + q1.y * k0.y + q1.z * k0.z + q1.w * k0.w;
            a11 += q1.x * k1.x + q1.y * k1.y + q1.z * k1.z + q1.w * k1.w;
        }
        const int j0 = jt * 128 + lane, j1 = j0 + 64;
        const float* bga = biasg + (((size_t)(b * HEADS + h)) * NTOK + ia) * NTOK;
        const float* bgb = bga + NTOK;
        S[0][2 * jt + 0] = a00 * scale + (adj[ia * NTOK + j0] > 0 ? bga[j0] : NEG_INF);
        S[0][2 * jt + 1] = a01 * scale + (adj[ia * NTOK + j1] > 0 ? bga[j1] : NEG_INF);
        S[1][2 * jt + 0] = a10 * scale + (adj[ib * NTOK + j0] > 0 ? bgb[j0] : NEG_INF);
        S[1][2 * jt + 1] = a11 * scale + (adj[ib * NTOK + j1] > 0 ? bgb[j1] : NEG_INF);
    }

    // ---- phase 2: softmax per row ----
    float p[2][8];
    #pragma unroll
    for (int r = 0; r < 2; ++r) {
        float mx = S[r][0];
        #pragma unroll
        for (int k = 1; k < 8; ++k) mx = fmaxf(mx, S[r][k]);
        for (int off = 32; off; off >>= 1) mx = fmaxf(mx, __shfl_xor(mx, off, 64));
        float l = 0.f;
        #pragma unroll
        for (int k = 0; k < 8; ++k) { p[r][k] = __expf(S[r][k] - mx); l += p[r][k]; }
        for (int off = 32; off; off >>= 1) l += __shfl_xor(l, off, 64);
        const float inv = 1.0f / l;
        #pragma unroll
        for (int k = 0; k < 8; ++k) p[r][k] *= inv;
    }

    // ---- phase 3: O = P @ V for both rows (lane = d) ----
    float o0 = 0.f, o1 = 0.f;
    for (int jt = 0; jt < 4; ++jt) {
        __syncthreads();
        for (int idx = t; idx < 128 * 16; idx += 256) {
            int r = idx >> 4, dq = idx & 15;
            ((float4*)Ks[r])[dq] =
                ((const float4*)(V + (b * NTOK + jt * 128 + r) * HID + h * HD))[dq];
        }
        __syncthreads();
        #pragma unroll
        for (int jr = 0; jr < 2; ++jr) {
            const float pa = p[0][2 * jt + jr];
            const float pb = p[1][2 * jt + jr];
            #pragma unroll 8
            for (int jj = 0; jj < 64; ++jj) {
                const float v = Ks[jr * 64 + jj][lane];
                o0 = fmaf(lane_bcast(pa, jj), v, o0);
                o1 = fmaf(lane_bcast(pb, jj), v, o1);
            }
        }
    }
    O[(b * NTOK + ia) * HID + h * HD + lane] = o0;
    O[(b * NTOK + ib) * HID + h * HD + lane] = o1;
}

// ---------------------------------------------------------------------------
// Stage D: out = O @ Wo + bo  (same 4x4 register tile as proj5)
// ---------------------------------------------------------------------------
__global__ __launch_bounds__(256) void pga_outproj(
    const float* __restrict__ Og, const float* __restrict__ Wo,
    const float* __restrict__ bo, float* __restrict__ out)
{
    __shared__ float xs[16][HID];
    const int m0 = blockIdx.x * 16;
    const int t = threadIdx.x;
    const int cg = t & 63;
    const int rg = t >> 6;

    {
        const float4* xg = (const float4*)(Og + m0 * HID);
        float4* xsv = (float4*)xs;
        #pragma unroll
        for (int k = 0; k < 4; ++k) xsv[t + 256 * k] = xg[t + 256 * k];
    }
    __syncthreads();

    const float4 bias4 = ((const float4*)bo)[cg];
    float4 acc[4] = {bias4, bias4, bias4, bias4};

    const float4* W4 = (const float4*)Wo;
    for (int kq = 0; kq < 64; ++kq) {
        const float4 w0 = W4[(4 * kq + 0) * 64 + cg];
        const float4 w1 = W4[(4 * kq + 1) * 64 + cg];
        const float4 w2 = W4[(4 * kq + 2) * 64 + cg];
        const float4 w3 = W4[(4 * kq + 3) * 64 + cg];
        #pragma unroll
        for (int r = 0; r < 4; ++r) {
            const float4 xv = ((const float4*)xs[4 * rg + r])[kq];
            acc[r].x = fmaf(xv.x, w0.x, fmaf(xv.y, w1.x, fmaf(xv.z, w2.x, fmaf(xv.w, w3.x, acc[r].x))));
            acc[r].y = fmaf(xv.x, w0.y, fmaf(xv.y, w1.y, fmaf(xv.z, w2.y, fmaf(xv.w, w3.y, acc[r].y))));
            acc[r].z = fmaf(xv.x, w0.z, fmaf(xv.y, w1.z, fmaf(xv.z, w2.z, fmaf(xv.w, w3.z, acc[r].z))));
            acc[r].w = fmaf(xv.x, w0.w, fmaf(xv.y, w1.w, fmaf(xv.z, w2.w, fmaf(xv.w, w3.w, acc[r].w))));
        }
    }
    #pragma unroll
    for (int r = 0; r < 4; ++r)
        ((float4*)(out + (m0 + 4 * rg + r) * HID))[cg] = acc[r];
}

extern "C" void kernel_launch(void* const* d_in, const int* in_sizes, int n_in,
                              void* d_out, int out_size, void* d_ws, size_t ws_size,
                              hipStream_t stream) {
    const float* x   = (const float*)d_in[0];
    const int*   adj = (const int*)d_in[1];
    const float* Wq  = (const float*)d_in[2];
    const float* bq  = (const float*)d_in[3];
    const float* Wk  = (const float*)d_in[4];
    const float* bk  = (const float*)d_in[5];
    const float* Wv  = (const float*)d_in[6];
    const float* bv  = (const float*)d_in[7];
    const float* Wo  = (const float*)d_in[8];
    const float* bo  = (const float*)d_in[9];
    const float* Wp1 = (const float*)d_in[10];
    const float* bp1 = (const float*)d_in[11];
    const float* Wp2 = (const float*)d_in[12];
    const float* bp2 = (const float*)d_in[13];
    float* out = (float*)d_out;

    // ws layout (floats): Q,K,V,A,BbT,O each 262144; bias 2097152; pairs; gcount
    float* ws   = (float*)d_ws;
    float* Q    = ws;
    float* K    = ws + 262144;
    float* V    = ws + 2 * 262144;
    float* A    = ws + 3 * 262144;
    float* BbT  = ws + 4 * 262144;
    float* O    = ws + 5 * 262144;
    float* bias = ws + 6 * 262144;
    int* pairs  = (int*)(ws + 6 * 262144 + 2097152);
    int* gcount = pairs + 262144;

    hipMemsetAsync(gcount, 0, sizeof(int), stream);
    pga_compact<<<512, 64, 0, stream>>>(adj, pairs, gcount);
    pga_proj5<<<dim3(64, 5), 256, 0, stream>>>(x, Wq, bq, Wk, bk, Wv, bv,
                                               Wp1, bp1, Q, K, V, A, BbT);
    pga_bias<<<2048, 256, 0, stream>>>(A, BbT, Wp2, bp2, pairs, gcount, bias);
    pga_attn<<<512, 256, 0, stream>>>(Q, K, V, bias, adj, O);
    pga_outproj<<<64, 256, 0, stream>>>(O, Wo, bo, out);
}

// Round 4
// 264.360 us; speedup vs baseline: 1.6544x; 1.6544x over previous
//
#include <hip/hip_runtime.h>
#include <hip/hip_bf16.h>
#include <math.h>

#define NTOK 512      // N
#define BATCH 2
#define HID 256
#define HEADS 4
#define HD 64
#define NEG_INF -1e9f

typedef short bf16x8 __attribute__((ext_vector_type(8)));
typedef short bf16x4 __attribute__((ext_vector_type(4)));
typedef float f32x4 __attribute__((ext_vector_type(4)));

__device__ __forceinline__ short f2bf(float f) {
    union { __hip_bfloat16 h; short s; } u;
    u.h = __float2bfloat16(f);
    return u.s;
}

// Branch-free gelu via Abramowitz-Stegun 7.1.26 erf (max erf err 1.5e-7).
__device__ __forceinline__ float fast_gelu(float x) {
    const float z = fabsf(x) * 0.70710678118654752f;
    const float t = __builtin_amdgcn_rcpf(fmaf(0.3275911f, z, 1.0f));
    float p = fmaf(1.061405429f, t, -1.453152027f);
    p = fmaf(p, t, 1.421413741f);
    p = fmaf(p, t, -0.284496736f);
    p = fmaf(p, t, 0.254829592f);
    p = p * t;
    const float E = __expf(-(z * z));
    const float phin = 0.5f * p * E;                 // Phi(-|x|)
    const float phi = (x >= 0.0f) ? 1.0f - phin : phin;
    return x * phi;
}

// ---------------------------------------------------------------------------
// Stage 0: per-row ordered compaction of adj. Deterministic, no atomics.
//   rowlist[i*512 + k] = k-th valid j of row i (ascending); rowcnt[i] = count.
// ---------------------------------------------------------------------------
__global__ void pga_compact(const int* __restrict__ adj,
                            int* __restrict__ rowlist, int* __restrict__ rowcnt)
{
    const int i = blockIdx.x;
    const int lane = threadIdx.x;
    const unsigned long long ltmask = (1ull << lane) - 1ull;
    int running = 0;
    for (int c = 0; c < 8; ++c) {
        const int j = c * 64 + lane;
        const bool m = adj[i * NTOK + j] > 0;
        const unsigned long long bm = __ballot(m);
        if (m) rowlist[i * NTOK + running + __popcll(bm & ltmask)] = j;
        running += __popcll(bm);
    }
    if (lane == 0) rowcnt[i] = running;
}

// ---------------------------------------------------------------------------
// Stage A: fused 5-way projection GEMM.  Y = X @ W (+bias)
//   4x4 register tile per thread.
// ---------------------------------------------------------------------------
__global__ __launch_bounds__(256) void pga_proj5(
    const float* __restrict__ x,
    const float* __restrict__ Wq, const float* __restrict__ bq,
    const float* __restrict__ Wk, const float* __restrict__ bk,
    const float* __restrict__ Wv, const float* __restrict__ bv,
    const float* __restrict__ Wp1, const float* __restrict__ bp1,
    float* __restrict__ Q, float* __restrict__ K, float* __restrict__ V,
    float* __restrict__ A, float* __restrict__ BbT)
{
    __shared__ float xs[16][HID];
    const int m0 = blockIdx.x * 16;
    const int which = blockIdx.y;
    const int t = threadIdx.x;
    const int cg = t & 63;
    const int rg = t >> 6;

    {
        const float4* xg = (const float4*)(x + m0 * HID);
        float4* xsv = (float4*)xs;
        #pragma unroll
        for (int k = 0; k < 4; ++k) xsv[t + 256 * k] = xg[t + 256 * k];
    }
    __syncthreads();

    const float* W; const float* bvec; float* out; bool transposed = false;
    switch (which) {
        case 0: W = Wq; bvec = bq; out = Q; break;
        case 1: W = Wk; bvec = bk; out = K; break;
        case 2: W = Wv; bvec = bv; out = V; break;
        case 3: W = Wp1; bvec = bp1; out = A; break;
        default: W = Wp1 + HID * HID; bvec = nullptr; out = BbT; transposed = true; break;
    }

    float4 bias4 = make_float4(0.f, 0.f, 0.f, 0.f);
    if (bvec) bias4 = ((const float4*)bvec)[cg];
    float4 acc[4] = {bias4, bias4, bias4, bias4};

    const float4* W4 = (const float4*)W;
    for (int kq = 0; kq < 64; ++kq) {
        const float4 w0 = W4[(4 * kq + 0) * 64 + cg];
        const float4 w1 = W4[(4 * kq + 1) * 64 + cg];
        const float4 w2 = W4[(4 * kq + 2) * 64 + cg];
        const float4 w3 = W4[(4 * kq + 3) * 64 + cg];
        #pragma unroll
        for (int r = 0; r < 4; ++r) {
            const float4 xv = ((const float4*)xs[4 * rg + r])[kq];
            acc[r].x = fmaf(xv.x, w0.x, fmaf(xv.y, w1.x, fmaf(xv.z, w2.x, fmaf(xv.w, w3.x, acc[r].x))));
            acc[r].y = fmaf(xv.x, w0.y, fmaf(xv.y, w1.y, fmaf(xv.z, w2.y, fmaf(xv.w, w3.y, acc[r].y))));
            acc[r].z = fmaf(xv.x, w0.z, fmaf(xv.y, w1.z, fmaf(xv.z, w2.z, fmaf(xv.w, w3.z, acc[r].z))));
            acc[r].w = fmaf(xv.x, w0.w, fmaf(xv.y, w1.w, fmaf(xv.z, w2.w, fmaf(xv.w, w3.w, acc[r].w))));
        }
    }

    if (!transposed) {
        #pragma unroll
        for (int r = 0; r < 4; ++r)
            ((float4*)(out + (m0 + 4 * rg + r) * HID))[cg] = acc[r];
    } else {
        const int b = m0 >= NTOK;
        const int n0 = m0 - b * NTOK;
        #pragma unroll
        for (int r = 0; r < 4; ++r) {
            const int row = n0 + 4 * rg + r;
            float* ob = BbT + b * (HID * NTOK);
            ob[(4 * cg + 0) * NTOK + row] = acc[r].x;
            ob[(4 * cg + 1) * NTOK + row] = acc[r].y;
            ob[(4 * cg + 2) * NTOK + row] = acc[r].z;
            ob[(4 * cg + 3) * NTOK + row] = acc[r].w;
        }
    }
}

// ---------------------------------------------------------------------------
// Stage B: physics bias over valid pairs, row-ordered (coalescing preserved).
//   grid = B*N blocks x 256 threads. Block (b,i): threads take valid j's in
//   ascending order from rowlist.
// ---------------------------------------------------------------------------
__global__ __launch_bounds__(256) void pga_bias(
    const float* __restrict__ A, const float* __restrict__ BbT,
    const float* __restrict__ Wp2, const float* __restrict__ bp2,
    const int* __restrict__ rowlist, const int* __restrict__ rowcnt,
    float* __restrict__ biasg)
{
    __shared__ float as[HID];
    __shared__ float4 wp[HID];

    const int t = threadIdx.x;
    const int b = blockIdx.x >> 9;
    const int i = blockIdx.x & 511;

    as[t] = A[(b * NTOK + i) * HID + t];
    wp[t] = ((const float4*)Wp2)[t];
    __syncthreads();

    const int cnt = rowcnt[i];
    const float* bb = BbT + b * (HID * NTOK);
    const float4 bp = *(const float4*)bp2;

    for (int idx = t; idx < cnt; idx += 256) {
        const int j = rowlist[i * NTOK + idx];
        float ah0 = 0.f, ah1 = 0.f, ah2 = 0.f, ah3 = 0.f;
        #pragma unroll 4
        for (int d = 0; d < HID; ++d) {
            const float g = fast_gelu(as[d] + bb[d * NTOK + j]);
            const float4 wv = wp[d];
            ah0 = fmaf(g, wv.x, ah0); ah1 = fmaf(g, wv.y, ah1);
            ah2 = fmaf(g, wv.z, ah2); ah3 = fmaf(g, wv.w, ah3);
        }
        float* o = biasg + (((size_t)b * HEADS) * NTOK + i) * NTOK + j;
        o[0 * NTOK * NTOK] = ah0 + bp.x;
        o[1 * NTOK * NTOK] = ah1 + bp.y;
        o[2 * NTOK * NTOK] = ah2 + bp.z;
        o[3 * NTOK * NTOK] = ah3 + bp.w;
    }
}

// ---------------------------------------------------------------------------
// Stage C: MFMA flash attention.  64 blocks = (b,h,qt of 64 rows), 256 thr.
//   Wave w: 16 q-rows. Per 128-j tile: stage K,V bf16 in LDS; QK^T via
//   mfma 16x16x32; online softmax on C-layout; P -> A-layout via per-wave
//   LDS; PV via mfma. Layouts per verified m89/m120 mappings:
//     C/D: col=lane&15, row=(lane>>4)*4+reg
//     A:   A[m=lane&15][k=(lane>>4)*8+j]   B: B[k=(lane>>4)*8+j][n=lane&15]
// ---------------------------------------------------------------------------
#define KT_STRIDE 72   // pad 64->72: row delta 36 dw = 4 mod 32 -> 2-way
#define VN_STRIDE 76   // pad 64->76: 8-row delta 304 dw = 16 mod 32 -> 2-way
#define PL_STRIDE 136  // pad 128->136: row delta 68 dw = 4 mod 32 -> 2-way

__global__ __launch_bounds__(256) void pga_attn(
    const float* __restrict__ Q, const float* __restrict__ K,
    const float* __restrict__ V, const float* __restrict__ biasg,
    const int* __restrict__ adj, float* __restrict__ O)
{
    __shared__ short Kt[128 * KT_STRIDE];
    __shared__ short Vn[128 * VN_STRIDE];
    __shared__ short Pl[4][16 * PL_STRIDE];

    const int blk = blockIdx.x;
    const int b = blk >> 5;
    const int h = (blk >> 3) & 3;
    const int qt = blk & 7;
    const int t = threadIdx.x;
    const int w = t >> 6;
    const int lane = t & 63;
    const int ln15 = lane & 15;
    const int quad = lane >> 4;

    const int i0w = qt * 64 + w * 16;          // wave's first q-row

    // ---- Q A-fragments (scale folded into bf16 conversion) ----
    bf16x8 aq0, aq1;
    {
        const float* qrow = Q + ((size_t)(b * NTOK) + i0w + ln15) * HID + h * HD;
        const int k0 = quad * 8;
        #pragma unroll
        for (int jj = 0; jj < 8; ++jj) {
            aq0[jj] = f2bf(qrow[k0 + jj] * 0.125f);
            aq1[jj] = f2bf(qrow[32 + k0 + jj] * 0.125f);
        }
    }

    float m_i[4], l_i[4];
    f32x4 o_acc[4];
    #pragma unroll
    for (int r = 0; r < 4; ++r) { m_i[r] = -3.0e38f; l_i[r] = 0.f; }
    #pragma unroll
    for (int dt = 0; dt < 4; ++dt) o_acc[dt] = (f32x4){0.f, 0.f, 0.f, 0.f};

    const float* bgb = biasg + ((size_t)(b * HEADS + h)) * NTOK * NTOK;

    for (int jt = 0; jt < 4; ++jt) {
        const int j0 = jt * 128;
        __syncthreads();
        // ---- stage K,V tile (flat coalesced reads, bf16 convert) ----
        for (int k = 0; k < 8; ++k) {
            const int flat4 = k * 256 + t;       // 2048 float4 = 128 rows x 16
            const int jl = flat4 >> 4, dq = flat4 & 15;
            const float4 kv = ((const float4*)(K + ((size_t)(b * NTOK) + j0 + jl) * HID + h * HD))[dq];
            const float4 vv = ((const float4*)(V + ((size_t)(b * NTOK) + j0 + jl) * HID + h * HD))[dq];
            bf16x4 ks, vs;
            ks[0] = f2bf(kv.x); ks[1] = f2bf(kv.y); ks[2] = f2bf(kv.z); ks[3] = f2bf(kv.w);
            vs[0] = f2bf(vv.x); vs[1] = f2bf(vv.y); vs[2] = f2bf(vv.z); vs[3] = f2bf(vv.w);
            *(bf16x4*)&Kt[jl * KT_STRIDE + dq * 4] = ks;
            *(bf16x4*)&Vn[jl * VN_STRIDE + dq * 4] = vs;
        }
        __syncthreads();

        // ---- S = Q K^T for 8 column subtiles ----
        f32x4 s[8];
        #pragma unroll
        for (int nt = 0; nt < 8; ++nt) {
            const int krow = nt * 16 + ln15;
            const bf16x8 bk0 = *(const bf16x8*)&Kt[krow * KT_STRIDE + quad * 8];
            const bf16x8 bk1 = *(const bf16x8*)&Kt[krow * KT_STRIDE + 32 + quad * 8];
            f32x4 acc = (f32x4){0.f, 0.f, 0.f, 0.f};
            acc = __builtin_amdgcn_mfma_f32_16x16x32_bf16(aq0, bk0, acc, 0, 0, 0);
            acc = __builtin_amdgcn_mfma_f32_16x16x32_bf16(aq1, bk1, acc, 0, 0, 0);
            s[nt] = acc;
        }

        // ---- add masked bias ----
        #pragma unroll
        for (int nt = 0; nt < 8; ++nt) {
            const int j = j0 + nt * 16 + ln15;
            #pragma unroll
            for (int r = 0; r < 4; ++r) {
                const int i = i0w + quad * 4 + r;
                const float bvv = bgb[(size_t)i * NTOK + j];
                const int mv = adj[i * NTOK + j];
                s[nt][r] += (mv > 0) ? bvv : NEG_INF;
            }
        }

        // ---- online softmax (rows distributed over 16-lane groups) ----
        float p[8][4];
        float alpha[4];
        #pragma unroll
        for (int r = 0; r < 4; ++r) {
            float mx = s[0][r];
            #pragma unroll
            for (int nt = 1; nt < 8; ++nt) mx = fmaxf(mx, s[nt][r]);
            #pragma unroll
            for (int off = 1; off < 16; off <<= 1) mx = fmaxf(mx, __shfl_xor(mx, off, 64));
            const float mnew = fmaxf(m_i[r], mx);
            alpha[r] = __expf(m_i[r] - mnew);
            float rs = 0.f;
            #pragma unroll
            for (int nt = 0; nt < 8; ++nt) { p[nt][r] = __expf(s[nt][r] - mnew); rs += p[nt][r]; }
            #pragma unroll
            for (int off = 1; off < 16; off <<= 1) rs += __shfl_xor(rs, off, 64);
            l_i[r] = l_i[r] * alpha[r] + rs;
            m_i[r] = mnew;
        }
        #pragma unroll
        for (int dt = 0; dt < 4; ++dt)
            #pragma unroll
            for (int r = 0; r < 4; ++r) o_acc[dt][r] *= alpha[r];

        // ---- P -> per-wave LDS (C-layout scatter), read back as A-frags ----
        #pragma unroll
        for (int nt = 0; nt < 8; ++nt)
            #pragma unroll
            for (int r = 0; r < 4; ++r)
                Pl[w][(quad * 4 + r) * PL_STRIDE + nt * 16 + ln15] = f2bf(p[nt][r]);

        bf16x8 ap[4];
        #pragma unroll
        for (int kt = 0; kt < 4; ++kt)
            ap[kt] = *(const bf16x8*)&Pl[w][ln15 * PL_STRIDE + kt * 32 + quad * 8];

        // ---- O += P V ----
        #pragma unroll
        for (int dt = 0; dt < 4; ++dt) {
            #pragma unroll
            for (int kt = 0; kt < 4; ++kt) {
                bf16x8 bv;
                #pragma unroll
                for (int jj = 0; jj < 8; ++jj)
                    bv[jj] = Vn[(kt * 32 + quad * 8 + jj) * VN_STRIDE + dt * 16 + ln15];
                o_acc[dt] = __builtin_amdgcn_mfma_f32_16x16x32_bf16(ap[kt], bv, o_acc[dt], 0, 0, 0);
            }
        }
    }

    // ---- epilogue: normalize, write O ----
    #pragma unroll
    for (int dt = 0; dt < 4; ++dt) {
        #pragma unroll
        for (int r = 0; r < 4; ++r) {
            const int i = i0w + quad * 4 + r;
            O[((size_t)(b * NTOK) + i) * HID + h * HD + dt * 16 + ln15] =
                o_acc[dt][r] / l_i[r];
        }
    }
}

// ---------------------------------------------------------------------------
// Stage D: out = O @ Wo + bo  (4x4 register tile)
// ---------------------------------------------------------------------------
__global__ __launch_bounds__(256) void pga_outproj(
    const float* __restrict__ Og, const float* __restrict__ Wo,
    const float* __restrict__ bo, float* __restrict__ out)
{
    __shared__ float xs[16][HID];
    const int m0 = blockIdx.x * 16;
    const int t = threadIdx.x;
    const int cg = t & 63;
    const int rg = t >> 6;

    {
        const float4* xg = (const float4*)(Og + m0 * HID);
        float4* xsv = (float4*)xs;
        #pragma unroll
        for (int k = 0; k < 4; ++k) xsv[t + 256 * k] = xg[t + 256 * k];
    }
    __syncthreads();

    const float4 bias4 = ((const float4*)bo)[cg];
    float4 acc[4] = {bias4, bias4, bias4, bias4};

    const float4* W4 = (const float4*)Wo;
    for (int kq = 0; kq < 64; ++kq) {
        const float4 w0 = W4[(4 * kq + 0) * 64 + cg];
        const float4 w1 = W4[(4 * kq + 1) * 64 + cg];
        const float4 w2 = W4[(4 * kq + 2) * 64 + cg];
        const float4 w3 = W4[(4 * kq + 3) * 64 + cg];
        #pragma unroll
        for (int r = 0; r < 4; ++r) {
            const float4 xv = ((const float4*)xs[4 * rg + r])[kq];
            acc[r].x = fmaf(xv.x, w0.x, fmaf(xv.y, w1.x, fmaf(xv.z, w2.x, fmaf(xv.w, w3.x, acc[r].x))));
            acc[r].y = fmaf(xv.x, w0.y, fmaf(xv.y, w1.y, fmaf(xv.z, w2.y, fmaf(xv.w, w3.y, acc[r].y))));
            acc[r].z = fmaf(xv.x, w0.z, fmaf(xv.y, w1.z, fmaf(xv.z, w2.z, fmaf(xv.w, w3.z, acc[r].z))));
            acc[r].w = fmaf(xv.x, w0.w, fmaf(xv.y, w1.w, fmaf(xv.z, w2.w, fmaf(xv.w, w3.w, acc[r].w))));
        }
    }
    #pragma unroll
    for (int r = 0; r < 4; ++r)
        ((float4*)(out + (m0 + 4 * rg + r) * HID))[cg] = acc[r];
}

extern "C" void kernel_launch(void* const* d_in, const int* in_sizes, int n_in,
                              void* d_out, int out_size, void* d_ws, size_t ws_size,
                              hipStream_t stream) {
    const float* x   = (const float*)d_in[0];
    const int*   adj = (const int*)d_in[1];
    const float* Wq  = (const float*)d_in[2];
    const float* bq  = (const float*)d_in[3];
    const float* Wk  = (const float*)d_in[4];
    const float* bk  = (const float*)d_in[5];
    const float* Wv  = (const float*)d_in[6];
    const float* bv  = (const float*)d_in[7];
    const float* Wo  = (const float*)d_in[8];
    const float* bo  = (const float*)d_in[9];
    const float* Wp1 = (const float*)d_in[10];
    const float* bp1 = (const float*)d_in[11];
    const float* Wp2 = (const float*)d_in[12];
    const float* bp2 = (const float*)d_in[13];
    float* out = (float*)d_out;

    // ws layout (floats): Q,K,V,A,BbT,O each 262144; bias 2097152; rowlist; rowcnt
    float* ws    = (float*)d_ws;
    float* Q     = ws;
    float* K     = ws + 262144;
    float* V     = ws + 2 * 262144;
    float* A     = ws + 3 * 262144;
    float* BbT   = ws + 4 * 262144;
    float* O     = ws + 5 * 262144;
    float* bias  = ws + 6 * 262144;
    int* rowlist = (int*)(ws + 6 * 262144 + 2097152);
    int* rowcnt  = rowlist + 262144;

    pga_compact<<<512, 64, 0, stream>>>(adj, rowlist, rowcnt);
    pga_proj5<<<dim3(64, 5), 256, 0, stream>>>(x, Wq, bq, Wk, bk, Wv, bv,
                                               Wp1, bp1, Q, K, V, A, BbT);
    pga_bias<<<1024, 256, 0, stream>>>(A, BbT, Wp2, bp2, rowlist, rowcnt, bias);
    pga_attn<<<64, 256, 0, stream>>>(Q, K, V, bias, adj, O);
    pga_outproj<<<64, 256, 0, stream>>>(O, Wo, bo, out);
}

// Round 5
// 251.512 us; speedup vs baseline: 1.7389x; 1.0511x over previous
//
#include <hip/hip_runtime.h>
#include <hip/hip_bf16.h>
#include <math.h>

#define NTOK 512      // N
#define BATCH 2
#define HID 256
#define HEADS 4
#define HD 64
#define NEG_INF -1e9f

typedef short bf16x8 __attribute__((ext_vector_type(8)));
typedef short bf16x4 __attribute__((ext_vector_type(4)));
typedef float f32x4 __attribute__((ext_vector_type(4)));

__device__ __forceinline__ short f2bf(float f) {
    union { __hip_bfloat16 h; short s; } u;
    u.h = __float2bfloat16(f);
    return u.s;
}

// Branch-free gelu via Abramowitz-Stegun 7.1.26 erf (max erf err 1.5e-7).
__device__ __forceinline__ float fast_gelu(float x) {
    const float z = fabsf(x) * 0.70710678118654752f;
    const float t = __builtin_amdgcn_rcpf(fmaf(0.3275911f, z, 1.0f));
    float p = fmaf(1.061405429f, t, -1.453152027f);
    p = fmaf(p, t, 1.421413741f);
    p = fmaf(p, t, -0.284496736f);
    p = fmaf(p, t, 0.254829592f);
    p = p * t;
    const float E = __expf(-(z * z));
    const float phin = 0.5f * p * E;                 // Phi(-|x|) in [0,0.5]
    const float phi = 0.5f + copysignf(0.5f - phin, x);
    return x * phi;
}

// ---------------------------------------------------------------------------
// Stage A: fused 5-way projection GEMM.  Y = X @ W (+bias)
//   4x4 register tile per thread.
// ---------------------------------------------------------------------------
__global__ __launch_bounds__(256) void pga_proj5(
    const float* __restrict__ x,
    const float* __restrict__ Wq, const float* __restrict__ bq,
    const float* __restrict__ Wk, const float* __restrict__ bk,
    const float* __restrict__ Wv, const float* __restrict__ bv,
    const float* __restrict__ Wp1, const float* __restrict__ bp1,
    float* __restrict__ Q, float* __restrict__ K, float* __restrict__ V,
    float* __restrict__ A, float* __restrict__ BbT)
{
    __shared__ float xs[16][HID];
    const int m0 = blockIdx.x * 16;
    const int which = blockIdx.y;
    const int t = threadIdx.x;
    const int cg = t & 63;
    const int rg = t >> 6;

    {
        const float4* xg = (const float4*)(x + m0 * HID);
        float4* xsv = (float4*)xs;
        #pragma unroll
        for (int k = 0; k < 4; ++k) xsv[t + 256 * k] = xg[t + 256 * k];
    }
    __syncthreads();

    const float* W; const float* bvec; float* out; bool transposed = false;
    switch (which) {
        case 0: W = Wq; bvec = bq; out = Q; break;
        case 1: W = Wk; bvec = bk; out = K; break;
        case 2: W = Wv; bvec = bv; out = V; break;
        case 3: W = Wp1; bvec = bp1; out = A; break;
        default: W = Wp1 + HID * HID; bvec = nullptr; out = BbT; transposed = true; break;
    }

    float4 bias4 = make_float4(0.f, 0.f, 0.f, 0.f);
    if (bvec) bias4 = ((const float4*)bvec)[cg];
    float4 acc[4] = {bias4, bias4, bias4, bias4};

    const float4* W4 = (const float4*)W;
    for (int kq = 0; kq < 64; ++kq) {
        const float4 w0 = W4[(4 * kq + 0) * 64 + cg];
        const float4 w1 = W4[(4 * kq + 1) * 64 + cg];
        const float4 w2 = W4[(4 * kq + 2) * 64 + cg];
        const float4 w3 = W4[(4 * kq + 3) * 64 + cg];
        #pragma unroll
        for (int r = 0; r < 4; ++r) {
            const float4 xv = ((const float4*)xs[4 * rg + r])[kq];
            acc[r].x = fmaf(xv.x, w0.x, fmaf(xv.y, w1.x, fmaf(xv.z, w2.x, fmaf(xv.w, w3.x, acc[r].x))));
            acc[r].y = fmaf(xv.x, w0.y, fmaf(xv.y, w1.y, fmaf(xv.z, w2.y, fmaf(xv.w, w3.y, acc[r].y))));
            acc[r].z = fmaf(xv.x, w0.z, fmaf(xv.y, w1.z, fmaf(xv.z, w2.z, fmaf(xv.w, w3.z, acc[r].z))));
            acc[r].w = fmaf(xv.x, w0.w, fmaf(xv.y, w1.w, fmaf(xv.z, w2.w, fmaf(xv.w, w3.w, acc[r].w))));
        }
    }

    if (!transposed) {
        #pragma unroll
        for (int r = 0; r < 4; ++r)
            ((float4*)(out + (m0 + 4 * rg + r) * HID))[cg] = acc[r];
    } else {
        const int b = m0 >= NTOK;
        const int n0 = m0 - b * NTOK;
        #pragma unroll
        for (int r = 0; r < 4; ++r) {
            const int row = n0 + 4 * rg + r;
            float* ob = BbT + b * (HID * NTOK);
            ob[(4 * cg + 0) * NTOK + row] = acc[r].x;
            ob[(4 * cg + 1) * NTOK + row] = acc[r].y;
            ob[(4 * cg + 2) * NTOK + row] = acc[r].z;
            ob[(4 * cg + 3) * NTOK + row] = acc[r].w;
        }
    }
}

// ---------------------------------------------------------------------------
// Stage B: physics bias over valid pairs. Two rows per block, self-compacted
//   into LDS (no separate compact kernel, no global rowlist).
//   grid = B*N/2 = 512 blocks x 512 threads. Combined valid count ~512+-16,
//   so the stride-512 work loop has ~3% tail waste (vs ~50% in R4).
// ---------------------------------------------------------------------------
__global__ __launch_bounds__(512) void pga_bias(
    const float* __restrict__ A, const float* __restrict__ BbT,
    const float* __restrict__ Wp2, const float* __restrict__ bp2,
    const int* __restrict__ adj, float* __restrict__ biasg)
{
    __shared__ float as[2][HID];
    __shared__ float4 wp[HID];
    __shared__ short jlist[2][NTOK];
    __shared__ int wcnt[2][8];

    const int t = threadIdx.x;
    const int b = blockIdx.x >> 8;
    const int rb = blockIdx.x & 255;
    const int i0 = rb * 2;
    const int w = t >> 6, lane = t & 63;
    const unsigned long long ltm = (1ull << lane) - 1ull;

    if (t < 2 * HID) as[t >> 8][t & 255] = A[(b * NTOK + i0 + (t >> 8)) * HID + (t & 255)];
    if (t < HID) wp[t] = ((const float4*)Wp2)[t];

    // ---- compact rows i0, i0+1 into LDS lists (ordered, deterministic) ----
    const bool m0 = adj[(i0 + 0) * NTOK + t] > 0;
    const bool m1 = adj[(i0 + 1) * NTOK + t] > 0;
    const unsigned long long bm0 = __ballot(m0);
    const unsigned long long bm1 = __ballot(m1);
    if (lane == 0) { wcnt[0][w] = __popcll(bm0); wcnt[1][w] = __popcll(bm1); }
    __syncthreads();
    int base0 = 0, base1 = 0, tot0 = 0, tot1 = 0;
    #pragma unroll
    for (int w2 = 0; w2 < 8; ++w2) {
        const int c0 = wcnt[0][w2], c1 = wcnt[1][w2];
        if (w2 < w) { base0 += c0; base1 += c1; }
        tot0 += c0; tot1 += c1;
    }
    if (m0) jlist[0][base0 + __popcll(bm0 & ltm)] = (short)t;
    if (m1) jlist[1][base1 + __popcll(bm1 & ltm)] = (short)t;
    __syncthreads();

    // ---- main: one valid pair per thread-iteration ----
    const int ct = tot0 + tot1;
    const float* bb = BbT + b * (HID * NTOK);
    const float4 bp = *(const float4*)bp2;

    for (int idx = t; idx < ct; idx += 512) {
        const int r = idx >= tot0;
        const int j = jlist[r][idx - (r ? tot0 : 0)];
        const float* asr = as[r];
        float ah0 = 0.f, ah1 = 0.f, ah2 = 0.f, ah3 = 0.f;
        #pragma unroll 4
        for (int d = 0; d < HID; ++d) {
            const float g = fast_gelu(asr[d] + bb[d * NTOK + j]);
            const float4 wv = wp[d];
            ah0 = fmaf(g, wv.x, ah0); ah1 = fmaf(g, wv.y, ah1);
            ah2 = fmaf(g, wv.z, ah2); ah3 = fmaf(g, wv.w, ah3);
        }
        const int i = i0 + r;
        float* o = biasg + (((size_t)b * HEADS) * NTOK + i) * NTOK + j;
        o[0 * NTOK * NTOK] = ah0 + bp.x;
        o[1 * NTOK * NTOK] = ah1 + bp.y;
        o[2 * NTOK * NTOK] = ah2 + bp.z;
        o[3 * NTOK * NTOK] = ah3 + bp.w;
    }
}

// ---------------------------------------------------------------------------
// Stage C: MFMA flash attention.  64 blocks = (b,h,qt of 64 rows), 256 thr.
//   Wave w: 16 q-rows. Per 128-j tile: stage K,V bf16 in LDS; QK^T via
//   mfma 16x16x32; online softmax on C-layout; P -> A-layout via per-wave
//   LDS; PV via mfma. Layouts per verified m89/m120 mappings:
//     C/D: col=lane&15, row=(lane>>4)*4+reg
//     A:   A[m=lane&15][k=(lane>>4)*8+j]   B: B[k=(lane>>4)*8+j][n=lane&15]
// ---------------------------------------------------------------------------
#define KT_STRIDE 72
#define VN_STRIDE 76
#define PL_STRIDE 136

__global__ __launch_bounds__(256) void pga_attn(
    const float* __restrict__ Q, const float* __restrict__ K,
    const float* __restrict__ V, const float* __restrict__ biasg,
    const int* __restrict__ adj, float* __restrict__ O)
{
    __shared__ short Kt[128 * KT_STRIDE];
    __shared__ short Vn[128 * VN_STRIDE];
    __shared__ short Pl[4][16 * PL_STRIDE];

    const int blk = blockIdx.x;
    const int b = blk >> 5;
    const int h = (blk >> 3) & 3;
    const int qt = blk & 7;
    const int t = threadIdx.x;
    const int w = t >> 6;
    const int lane = t & 63;
    const int ln15 = lane & 15;
    const int quad = lane >> 4;

    const int i0w = qt * 64 + w * 16;          // wave's first q-row

    // ---- Q A-fragments (scale folded into bf16 conversion) ----
    bf16x8 aq0, aq1;
    {
        const float* qrow = Q + ((size_t)(b * NTOK) + i0w + ln15) * HID + h * HD;
        const int k0 = quad * 8;
        #pragma unroll
        for (int jj = 0; jj < 8; ++jj) {
            aq0[jj] = f2bf(qrow[k0 + jj] * 0.125f);
            aq1[jj] = f2bf(qrow[32 + k0 + jj] * 0.125f);
        }
    }

    float m_i[4], l_i[4];
    f32x4 o_acc[4];
    #pragma unroll
    for (int r = 0; r < 4; ++r) { m_i[r] = -3.0e38f; l_i[r] = 0.f; }
    #pragma unroll
    for (int dt = 0; dt < 4; ++dt) o_acc[dt] = (f32x4){0.f, 0.f, 0.f, 0.f};

    const float* bgb = biasg + ((size_t)(b * HEADS + h)) * NTOK * NTOK;

    for (int jt = 0; jt < 4; ++jt) {
        const int j0 = jt * 128;
        __syncthreads();
        // ---- stage K,V tile (flat coalesced reads, bf16 convert) ----
        for (int k = 0; k < 8; ++k) {
            const int flat4 = k * 256 + t;       // 2048 float4 = 128 rows x 16
            const int jl = flat4 >> 4, dq = flat4 & 15;
            const float4 kv = ((const float4*)(K + ((size_t)(b * NTOK) + j0 + jl) * HID + h * HD))[dq];
            const float4 vv = ((const float4*)(V + ((size_t)(b * NTOK) + j0 + jl) * HID + h * HD))[dq];
            bf16x4 ks, vs;
            ks[0] = f2bf(kv.x); ks[1] = f2bf(kv.y); ks[2] = f2bf(kv.z); ks[3] = f2bf(kv.w);
            vs[0] = f2bf(vv.x); vs[1] = f2bf(vv.y); vs[2] = f2bf(vv.z); vs[3] = f2bf(vv.w);
            *(bf16x4*)&Kt[jl * KT_STRIDE + dq * 4] = ks;
            *(bf16x4*)&Vn[jl * VN_STRIDE + dq * 4] = vs;
        }
        __syncthreads();

        // ---- S = Q K^T for 8 column subtiles ----
        f32x4 s[8];
        #pragma unroll
        for (int nt = 0; nt < 8; ++nt) {
            const int krow = nt * 16 + ln15;
            const bf16x8 bk0 = *(const bf16x8*)&Kt[krow * KT_STRIDE + quad * 8];
            const bf16x8 bk1 = *(const bf16x8*)&Kt[krow * KT_STRIDE + 32 + quad * 8];
            f32x4 acc = (f32x4){0.f, 0.f, 0.f, 0.f};
            acc = __builtin_amdgcn_mfma_f32_16x16x32_bf16(aq0, bk0, acc, 0, 0, 0);
            acc = __builtin_amdgcn_mfma_f32_16x16x32_bf16(aq1, bk1, acc, 0, 0, 0);
            s[nt] = acc;
        }

        // ---- add masked bias ----
        #pragma unroll
        for (int nt = 0; nt < 8; ++nt) {
            const int j = j0 + nt * 16 + ln15;
            #pragma unroll
            for (int r = 0; r < 4; ++r) {
                const int i = i0w + quad * 4 + r;
                const float bvv = bgb[(size_t)i * NTOK + j];
                const int mv = adj[i * NTOK + j];
                s[nt][r] += (mv > 0) ? bvv : NEG_INF;
            }
        }

        // ---- online softmax (rows distributed over 16-lane groups) ----
        float p[8][4];
        float alpha[4];
        #pragma unroll
        for (int r = 0; r < 4; ++r) {
            float mx = s[0][r];
            #pragma unroll
            for (int nt = 1; nt < 8; ++nt) mx = fmaxf(mx, s[nt][r]);
            #pragma unroll
            for (int off = 1; off < 16; off <<= 1) mx = fmaxf(mx, __shfl_xor(mx, off, 64));
            const float mnew = fmaxf(m_i[r], mx);
            alpha[r] = __expf(m_i[r] - mnew);
            float rs = 0.f;
            #pragma unroll
            for (int nt = 0; nt < 8; ++nt) { p[nt][r] = __expf(s[nt][r] - mnew); rs += p[nt][r]; }
            #pragma unroll
            for (int off = 1; off < 16; off <<= 1) rs += __shfl_xor(rs, off, 64);
            l_i[r] = l_i[r] * alpha[r] + rs;
            m_i[r] = mnew;
        }
        #pragma unroll
        for (int dt = 0; dt < 4; ++dt)
            #pragma unroll
            for (int r = 0; r < 4; ++r) o_acc[dt][r] *= alpha[r];

        // ---- P -> per-wave LDS (C-layout scatter), read back as A-frags ----
        #pragma unroll
        for (int nt = 0; nt < 8; ++nt)
            #pragma unroll
            for (int r = 0; r < 4; ++r)
                Pl[w][(quad * 4 + r) * PL_STRIDE + nt * 16 + ln15] = f2bf(p[nt][r]);

        bf16x8 ap[4];
        #pragma unroll
        for (int kt = 0; kt < 4; ++kt)
            ap[kt] = *(const bf16x8*)&Pl[w][ln15 * PL_STRIDE + kt * 32 + quad * 8];

        // ---- O += P V ----
        #pragma unroll
        for (int dt = 0; dt < 4; ++dt) {
            #pragma unroll
            for (int kt = 0; kt < 4; ++kt) {
                bf16x8 bv;
                #pragma unroll
                for (int jj = 0; jj < 8; ++jj)
                    bv[jj] = Vn[(kt * 32 + quad * 8 + jj) * VN_STRIDE + dt * 16 + ln15];
                o_acc[dt] = __builtin_amdgcn_mfma_f32_16x16x32_bf16(ap[kt], bv, o_acc[dt], 0, 0, 0);
            }
        }
    }

    // ---- epilogue: normalize, write O ----
    #pragma unroll
    for (int dt = 0; dt < 4; ++dt) {
        #pragma unroll
        for (int r = 0; r < 4; ++r) {
            const int i = i0w + quad * 4 + r;
            O[((size_t)(b * NTOK) + i) * HID + h * HD + dt * 16 + ln15] =
                o_acc[dt][r] / l_i[r];
        }
    }
}

// ---------------------------------------------------------------------------
// Stage D: out = O @ Wo + bo  (4x4 register tile)
// ---------------------------------------------------------------------------
__global__ __launch_bounds__(256) void pga_outproj(
    const float* __restrict__ Og, const float* __restrict__ Wo,
    const float* __restrict__ bo, float* __restrict__ out)
{
    __shared__ float xs[16][HID];
    const int m0 = blockIdx.x * 16;
    const int t = threadIdx.x;
    const int cg = t & 63;
    const int rg = t >> 6;

    {
        const float4* xg = (const float4*)(Og + m0 * HID);
        float4* xsv = (float4*)xs;
        #pragma unroll
        for (int k = 0; k < 4; ++k) xsv[t + 256 * k] = xg[t + 256 * k];
    }
    __syncthreads();

    const float4 bias4 = ((const float4*)bo)[cg];
    float4 acc[4] = {bias4, bias4, bias4, bias4};

    const float4* W4 = (const float4*)Wo;
    for (int kq = 0; kq < 64; ++kq) {
        const float4 w0 = W4[(4 * kq + 0) * 64 + cg];
        const float4 w1 = W4[(4 * kq + 1) * 64 + cg];
        const float4 w2 = W4[(4 * kq + 2) * 64 + cg];
        const float4 w3 = W4[(4 * kq + 3) * 64 + cg];
        #pragma unroll
        for (int r = 0; r < 4; ++r) {
            const float4 xv = ((const float4*)xs[4 * rg + r])[kq];
            acc[r].x = fmaf(xv.x, w0.x, fmaf(xv.y, w1.x, fmaf(xv.z, w2.x, fmaf(xv.w, w3.x, acc[r].x))));
            acc[r].y = fmaf(xv.x, w0.y, fmaf(xv.y, w1.y, fmaf(xv.z, w2.y, fmaf(xv.w, w3.y, acc[r].y))));
            acc[r].z = fmaf(xv.x, w0.z, fmaf(xv.y, w1.z, fmaf(xv.z, w2.z, fmaf(xv.w, w3.z, acc[r].z))));
            acc[r].w = fmaf(xv.x, w0.w, fmaf(xv.y, w1.w, fmaf(xv.z, w2.w, fmaf(xv.w, w3.w, acc[r].w))));
        }
    }
    #pragma unroll
    for (int r = 0; r < 4; ++r)
        ((float4*)(out + (m0 + 4 * rg + r) * HID))[cg] = acc[r];
}

extern "C" void kernel_launch(void* const* d_in, const int* in_sizes, int n_in,
                              void* d_out, int out_size, void* d_ws, size_t ws_size,
                              hipStream_t stream) {
    const float* x   = (const float*)d_in[0];
    const int*   adj = (const int*)d_in[1];
    const float* Wq  = (const float*)d_in[2];
    const float* bq  = (const float*)d_in[3];
    const float* Wk  = (const float*)d_in[4];
    const float* bk  = (const float*)d_in[5];
    const float* Wv  = (const float*)d_in[6];
    const float* bv  = (const float*)d_in[7];
    const float* Wo  = (const float*)d_in[8];
    const float* bo  = (const float*)d_in[9];
    const float* Wp1 = (const float*)d_in[10];
    const float* bp1 = (const float*)d_in[11];
    const float* Wp2 = (const float*)d_in[12];
    const float* bp2 = (const float*)d_in[13];
    float* out = (float*)d_out;

    // ws layout (floats): Q,K,V,A,BbT,O each 262144; bias 2097152
    float* ws    = (float*)d_ws;
    float* Q     = ws;
    float* K     = ws + 262144;
    float* V     = ws + 2 * 262144;
    float* A     = ws + 3 * 262144;
    float* BbT   = ws + 4 * 262144;
    float* O     = ws + 5 * 262144;
    float* bias  = ws + 6 * 262144;

    pga_proj5<<<dim3(64, 5), 256, 0, stream>>>(x, Wq, bq, Wk, bk, Wv, bv,
                                               Wp1, bp1, Q, K, V, A, BbT);
    pga_bias<<<512, 512, 0, stream>>>(A, BbT, Wp2, bp2, adj, bias);
    pga_attn<<<64, 256, 0, stream>>>(Q, K, V, bias, adj, O);
    pga_outproj<<<64, 256, 0, stream>>>(O, Wo, bo, out);
}